// Round 4
// baseline (284.793 us; speedup 1.0000x reference)
//
#include <hip/hip_runtime.h>
#include <stdint.h>
#include <math.h>

#define NPTS   16384
#define NBATCH 64
#define NITER  256
#define NSAMP  6
#define PPT    8

// ---------------- Threefry-2x32 (exact JAX semantics) ----------------
__device__ __forceinline__ uint32_t rotl32(uint32_t v, uint32_t r) {
  return (v << r) | (v >> (32u - r));
}
__device__ __forceinline__ void tf_round(uint32_t& x0, uint32_t& x1, uint32_t r) {
  x0 += x1; x1 = rotl32(x1, r); x1 ^= x0;
}
__device__ void threefry2x32(uint32_t k0, uint32_t k1, uint32_t x0, uint32_t x1,
                             uint32_t& o0, uint32_t& o1) {
  uint32_t ks2 = k0 ^ k1 ^ 0x1BD11BDAu;
  x0 += k0; x1 += k1;
  tf_round(x0,x1,13); tf_round(x0,x1,15); tf_round(x0,x1,26); tf_round(x0,x1,6);
  x0 += k1; x1 += ks2 + 1u;
  tf_round(x0,x1,17); tf_round(x0,x1,29); tf_round(x0,x1,16); tf_round(x0,x1,24);
  x0 += ks2; x1 += k0 + 2u;
  tf_round(x0,x1,13); tf_round(x0,x1,15); tf_round(x0,x1,26); tf_round(x0,x1,6);
  x0 += k0; x1 += k1 + 3u;
  tf_round(x0,x1,17); tf_round(x0,x1,29); tf_round(x0,x1,16); tf_round(x0,x1,24);
  x0 += k1; x1 += ks2 + 4u;
  tf_round(x0,x1,13); tf_round(x0,x1,15); tf_round(x0,x1,26); tf_round(x0,x1,6);
  x0 += ks2; x1 += k0 + 5u;
  o0 = x0; o1 = x1;
}

// ---------------- 3x3 Jacobi rotation (compile-time indices) ----------------
template<int P, int Q>
__device__ __forceinline__ void jrot(double S[3][3], double V[3][3]) {
  double apq = S[P][Q];
  if (fabs(apq) > 1e-300) {
    double tau = (S[Q][Q] - S[P][P]) / (2.0 * apq);
    double t = copysign(1.0, tau) / (fabs(tau) + sqrt(1.0 + tau * tau));
    double c = 1.0 / sqrt(1.0 + t * t);
    double sn = t * c;
    #pragma unroll
    for (int k = 0; k < 3; ++k) {
      double skp = S[k][P], skq = S[k][Q];
      S[k][P] = c * skp - sn * skq;
      S[k][Q] = sn * skp + c * skq;
    }
    #pragma unroll
    for (int k = 0; k < 3; ++k) {
      double spk = S[P][k], sqk = S[Q][k];
      S[P][k] = c * spk - sn * sqk;
      S[Q][k] = sn * spk + c * sqk;
    }
    #pragma unroll
    for (int k = 0; k < 3; ++k) {
      double vkp = V[k][P], vkq = V[k][Q];
      V[k][P] = c * vkp - sn * vkq;
      V[k][Q] = sn * vkp + c * vkq;
    }
  }
}

__device__ __forceinline__ void swapd(double& a, double& b) { double t=a; a=b; b=t; }

// ---------------- Kernel 1: model fit (one thread per (batch, iter)) ----------------
__global__ __launch_bounds__(256) void fit_kernel(
    const float* __restrict__ src, const float* __restrict__ trg,
    const float* __restrict__ wts, const float* __restrict__ Tsv,
    float* __restrict__ models /* [NBATCH][NITER][12] */) {
  const int b = blockIdx.x;
  const int iter = threadIdx.x;

  // k2 = split(key(42))[1] under partitionable (fold-like) split:
  // element 1 of the split hashes counter (hi=0, lo=1).
  uint32_t K0, K1;
  threefry2x32(0u, 42u, 0u, 1u, K0, K1);

  // randint(k2, (256,64,6), 0, 16384): span=2^14 divides 2^16 => multiplier=0,
  // idx = lower_bits % span; partitionable 32-bit bits = o0 ^ o1 of
  // threefry(k2, (0, flat_position)).
  const uint32_t base = (uint32_t)((iter * NBATCH + b) * NSAMP);
  int idx[NSAMP];
  #pragma unroll
  for (int s = 0; s < NSAMP; ++s) {
    uint32_t y0, y1;
    threefry2x32(K0, K1, 0u, base + (uint32_t)s, y0, y1);
    idx[s] = (int)((y0 ^ y1) & (uint32_t)(NPTS - 1));
  }

  const float* sb = src + (size_t)b * 4 * NPTS;
  const float* tb = trg + (size_t)b * 4 * NPTS;
  const float* wb = wts + (size_t)b * NPTS;

  // gather samples (keep as f32 to save registers; lossless)
  float px[NSAMP], py[NSAMP], pz[NSAMP], qx[NSAMP], qy[NSAMP], qz[NSAMP], wv[NSAMP];
  #pragma unroll
  for (int s = 0; s < NSAMP; ++s) {
    int j = idx[s];
    px[s] = sb[j]; py[s] = sb[NPTS + j]; pz[s] = sb[2 * NPTS + j];
    qx[s] = tb[j]; qy[s] = tb[NPTS + j]; qz[s] = tb[2 * NPTS + j];
    wv[s] = wb[j];
  }

  // weighted centroids (fp64)
  double wsum = 0, csx = 0, csy = 0, csz = 0, ctx = 0, cty = 0, ctz = 0;
  #pragma unroll
  for (int s = 0; s < NSAMP; ++s) {
    double w = (double)wv[s];
    wsum += w;
    csx += (double)px[s] * w; csy += (double)py[s] * w; csz += (double)pz[s] * w;
    ctx += (double)qx[s] * w; cty += (double)qy[s] * w; ctz += (double)qz[s] * w;
  }
  double iw = 1.0 / wsum;
  csx *= iw; csy *= iw; csz *= iw; ctx *= iw; cty *= iw; ctz *= iw;

  // cov[i][j] = sum_s (qt_i * w) * qs_j   (target rows i, source cols j)
  double C00=0,C01=0,C02=0,C10=0,C11=0,C12=0,C20=0,C21=0,C22=0;
  #pragma unroll
  for (int s = 0; s < NSAMP; ++s) {
    double w = (double)wv[s];
    double ax = ((double)qx[s]-ctx)*w, ay = ((double)qy[s]-cty)*w, az = ((double)qz[s]-ctz)*w;
    double bx = (double)px[s]-csx, by = (double)py[s]-csy, bz = (double)pz[s]-csz;
    C00 += ax*bx; C01 += ax*by; C02 += ax*bz;
    C10 += ay*bx; C11 += ay*by; C12 += ay*bz;
    C20 += az*bx; C21 += az*by; C22 += az*bz;
  }

  // S = C^T C, Jacobi eigendecomposition -> V (columns), eigenvalues on diag
  double S[3][3], V[3][3] = {{1,0,0},{0,1,0},{0,0,1}};
  S[0][0] = C00*C00 + C10*C10 + C20*C20;
  S[0][1] = C00*C01 + C10*C11 + C20*C21;
  S[0][2] = C00*C02 + C10*C12 + C20*C22;
  S[1][1] = C01*C01 + C11*C11 + C21*C21;
  S[1][2] = C01*C02 + C11*C12 + C21*C22;
  S[2][2] = C02*C02 + C12*C12 + C22*C22;
  S[1][0] = S[0][1]; S[2][0] = S[0][2]; S[2][1] = S[1][2];
  #pragma unroll 1
  for (int sweep = 0; sweep < 10; ++sweep) {
    jrot<0,1>(S, V); jrot<0,2>(S, V); jrot<1,2>(S, V);
  }

  double l0 = S[0][0], l1 = S[1][1], l2 = S[2][2];
  double v0x=V[0][0], v0y=V[1][0], v0z=V[2][0];
  double v1x=V[0][1], v1y=V[1][1], v1z=V[2][1];
  double v2x=V[0][2], v2y=V[1][2], v2z=V[2][2];
  // sort eigenvalues descending (column swaps)
  if (l0 < l1) { swapd(l0,l1); swapd(v0x,v1x); swapd(v0y,v1y); swapd(v0z,v1z); }
  if (l1 < l2) { swapd(l1,l2); swapd(v1x,v2x); swapd(v1y,v2y); swapd(v1z,v2z); }
  if (l0 < l1) { swapd(l0,l1); swapd(v0x,v1x); swapd(v0y,v1y); swapd(v0z,v1z); }

  // u0 = normalize(C v0); u1 = orthonormalize(C v1); u2 = u0 x u1; d = det(V)
  double u0x = C00*v0x + C01*v0y + C02*v0z;
  double u0y = C10*v0x + C11*v0y + C12*v0z;
  double u0z = C20*v0x + C21*v0y + C22*v0z;
  double n0 = sqrt(u0x*u0x + u0y*u0y + u0z*u0z);
  double r0 = (n0 > 1e-150) ? 1.0 / n0 : 0.0;
  u0x *= r0; u0y *= r0; u0z *= r0;
  double u1x = C00*v1x + C01*v1y + C02*v1z;
  double u1y = C10*v1x + C11*v1y + C12*v1z;
  double u1z = C20*v1x + C21*v1y + C22*v1z;
  double d01 = u1x*u0x + u1y*u0y + u1z*u0z;
  u1x -= d01*u0x; u1y -= d01*u0y; u1z -= d01*u0z;
  double n1 = sqrt(u1x*u1x + u1y*u1y + u1z*u1z);
  double r1 = (n1 > 1e-150) ? 1.0 / n1 : 0.0;
  u1x *= r1; u1y *= r1; u1z *= r1;
  double u2x = u0y*u1z - u0z*u1y;
  double u2y = u0z*u1x - u0x*u1z;
  double u2z = u0x*u1y - u0y*u1x;
  double detV = v0x*(v1y*v2z - v1z*v2y) - v0y*(v1x*v2z - v1z*v2x) + v0z*(v1x*v2y - v1y*v2x);
  // R = u0 v0^T + u1 v1^T + detV * u2 v2^T  (== U diag(1,1,det(U Vt)) Vt)
  double R00 = u0x*v0x + u1x*v1x + detV*u2x*v2x;
  double R01 = u0x*v0y + u1x*v1y + detV*u2x*v2y;
  double R02 = u0x*v0z + u1x*v1z + detV*u2x*v2z;
  double R10 = u0y*v0x + u1y*v1x + detV*u2y*v2x;
  double R11 = u0y*v0y + u1y*v1y + detV*u2y*v2y;
  double R12 = u0y*v0z + u1y*v1z + detV*u2y*v2z;
  double R20 = u0z*v0x + u1z*v1x + detV*u2z*v2x;
  double R21 = u0z*v0y + u1z*v1y + detV*u2z*v2y;
  double R22 = u0z*v0z + u1z*v1z + detV*u2z*v2z;
  double tx = ctx - (R00*csx + R01*csy + R02*csz);
  double ty = cty - (R10*csx + R11*csy + R12*csz);
  double tz = ctz - (R20*csx + R21*csy + R22*csz);

  // T_cam = T_s_v @ T_ts @ inv(T_s_v)
  double A[4][4];
  #pragma unroll
  for (int i = 0; i < 4; ++i)
    #pragma unroll
    for (int j = 0; j < 4; ++j) A[i][j] = (double)Tsv[i*4 + j];
  double Tts[4][4] = {{R00,R01,R02,tx},{R10,R11,R12,ty},{R20,R21,R22,tz},{0,0,0,1}};
  double I[4][4];
  I[0][0]=A[0][0]; I[0][1]=A[1][0]; I[0][2]=A[2][0];
  I[1][0]=A[0][1]; I[1][1]=A[1][1]; I[1][2]=A[2][1];
  I[2][0]=A[0][2]; I[2][1]=A[1][2]; I[2][2]=A[2][2];
  I[0][3] = -(I[0][0]*A[0][3] + I[0][1]*A[1][3] + I[0][2]*A[2][3]);
  I[1][3] = -(I[1][0]*A[0][3] + I[1][1]*A[1][3] + I[1][2]*A[2][3]);
  I[2][3] = -(I[2][0]*A[0][3] + I[2][1]*A[1][3] + I[2][2]*A[2][3]);
  I[3][0]=0; I[3][1]=0; I[3][2]=0; I[3][3]=1;
  double M1[4][4];
  #pragma unroll
  for (int i = 0; i < 4; ++i)
    #pragma unroll
    for (int j = 0; j < 4; ++j)
      M1[i][j] = A[i][0]*Tts[0][j] + A[i][1]*Tts[1][j] + A[i][2]*Tts[2][j] + A[i][3]*Tts[3][j];
  float* mo = models + ((size_t)b * NITER + iter) * 12;
  #pragma unroll
  for (int i = 0; i < 3; ++i)
    #pragma unroll
    for (int j = 0; j < 4; ++j)
      mo[i*4 + j] = (float)(M1[i][0]*I[0][j] + M1[i][1]*I[1][j] + M1[i][2]*I[2][j] + M1[i][3]*I[3][j]);
}

// ---------------- Kernel 2: inlier counts ----------------
__global__ __launch_bounds__(256) void count_kernel(
    const float* __restrict__ src, const float* __restrict__ trg,
    const int* __restrict__ vs, const int* __restrict__ vt,
    const float* __restrict__ models, int* __restrict__ counts) {
  __shared__ float M[NITER * 12];
  __shared__ int cl[NITER];
  const int b = blockIdx.x >> 3;
  const int chunk = blockIdx.x & 7;
  const float* mb = models + (size_t)b * NITER * 12;
  for (int i = threadIdx.x; i < NITER * 12; i += 256) M[i] = mb[i];
  for (int i = threadIdx.x; i < NITER; i += 256) cl[i] = 0;
  __syncthreads();

  const float* sb = src + (size_t)b * 4 * NPTS;
  const float* tb = trg + (size_t)b * 4 * NPTS;
  const int* vsb = vs + (size_t)b * NPTS;
  const int* vtb = vt + (size_t)b * NPTS;
  const int p0 = chunk * (256 * PPT) + threadIdx.x;

  float sx[PPT], sy[PPT], sz[PPT], tx[PPT], ty[PPT], tz[PPT];
  bool vd[PPT];
  #pragma unroll
  for (int k = 0; k < PPT; ++k) {
    int p = p0 + k * 256;
    sx[k] = sb[p]; sy[k] = sb[NPTS + p]; sz[k] = sb[2 * NPTS + p];
    tx[k] = tb[p]; ty[k] = tb[NPTS + p]; tz[k] = tb[2 * NPTS + p];
    vd[k] = (vsb[p] > 0) && (vtb[p] > 0);
  }

  for (int it = 0; it < NITER; ++it) {
    const float* m = &M[it * 12];
    float m00=m[0], m01=m[1], m02=m[2],  m03=m[3];
    float m10=m[4], m11=m[5], m12=m[6],  m13=m[7];
    float m20=m[8], m21=m[9], m22=m[10], m23=m[11];
    int c = 0;
    #pragma unroll
    for (int k = 0; k < PPT; ++k) {
      float ex = fmaf(m00, sx[k], fmaf(m01, sy[k], fmaf(m02, sz[k], m03)));
      float ey = fmaf(m10, sx[k], fmaf(m11, sy[k], fmaf(m12, sz[k], m13)));
      float ez = fmaf(m20, sx[k], fmaf(m21, sy[k], fmaf(m22, sz[k], m23)));
      float dx = tx[k] - ex, dy = ty[k] - ey, dz = tz[k] - ez;
      float e2 = fmaf(dx, dx, fmaf(dy, dy, dz * dz));
      c += (e2 < 0.25f && vd[k]) ? 1 : 0;
    }
    c += __shfl_xor(c, 32); c += __shfl_xor(c, 16); c += __shfl_xor(c, 8);
    c += __shfl_xor(c, 4);  c += __shfl_xor(c, 2);  c += __shfl_xor(c, 1);
    if ((threadIdx.x & 63) == 0) atomicAdd(&cl[it], c);
  }
  __syncthreads();
  for (int i = threadIdx.x; i < NITER; i += 256)
    atomicAdd(&counts[(size_t)b * NITER + i], cl[i]);
}

// ---------------- Kernel 3: argmax (strict >, first max wins) ----------------
__global__ __launch_bounds__(64) void argmax_kernel(const int* __restrict__ counts,
                                                    int* __restrict__ win) {
  const int b = blockIdx.x;
  int best = -1;
  for (int it = threadIdx.x; it < NITER; it += 64) {
    int c = counts[b * NITER + it];
    int key = (c << 8) | (NITER - 1 - it);  // max count, then earliest iter
    best = max(best, key);
  }
  best = max(best, __shfl_xor(best, 32));
  best = max(best, __shfl_xor(best, 16));
  best = max(best, __shfl_xor(best, 8));
  best = max(best, __shfl_xor(best, 4));
  best = max(best, __shfl_xor(best, 2));
  best = max(best, __shfl_xor(best, 1));
  if (threadIdx.x == 0) win[b] = (NITER - 1) - (best & 255);
}

// ---------------- Kernel 4: write winning mask ----------------
__global__ __launch_bounds__(256) void output_kernel(
    const float* __restrict__ src, const float* __restrict__ trg,
    const int* __restrict__ vs, const int* __restrict__ vt,
    const float* __restrict__ models, const int* __restrict__ win,
    float* __restrict__ out) {
  const int tid = blockIdx.x * 256 + threadIdx.x;
  const int b = tid >> 14;
  const int p = tid & (NPTS - 1);
  const int it = win[b];
  const float* m = models + ((size_t)b * NITER + it) * 12;
  float m00=m[0], m01=m[1], m02=m[2],  m03=m[3];
  float m10=m[4], m11=m[5], m12=m[6],  m13=m[7];
  float m20=m[8], m21=m[9], m22=m[10], m23=m[11];
  const float* sb = src + (size_t)b * 4 * NPTS;
  const float* tb = trg + (size_t)b * 4 * NPTS;
  float sxv = sb[p], syv = sb[NPTS + p], szv = sb[2 * NPTS + p];
  float txv = tb[p], tyv = tb[NPTS + p], tzv = tb[2 * NPTS + p];
  bool v = (vs[(size_t)b * NPTS + p] > 0) && (vt[(size_t)b * NPTS + p] > 0);
  float ex = fmaf(m00, sxv, fmaf(m01, syv, fmaf(m02, szv, m03)));
  float ey = fmaf(m10, sxv, fmaf(m11, syv, fmaf(m12, szv, m13)));
  float ez = fmaf(m20, sxv, fmaf(m21, syv, fmaf(m22, szv, m23)));
  float dx = txv - ex, dy = tyv - ey, dz = tzv - ez;
  float e2 = fmaf(dx, dx, fmaf(dy, dy, dz * dz));
  out[tid] = (e2 < 0.25f && v) ? 1.0f : 0.0f;
}

extern "C" void kernel_launch(void* const* d_in, const int* in_sizes, int n_in,
                              void* d_out, int out_size, void* d_ws, size_t ws_size,
                              hipStream_t stream) {
  (void)in_sizes; (void)n_in; (void)out_size; (void)ws_size;
  const float* src = (const float*)d_in[0];
  const float* trg = (const float*)d_in[1];
  // d_in[2] = keypoints_2D_trg, unused (DIM == '3D')
  const int*   vs  = (const int*)d_in[3];
  const int*   vt  = (const int*)d_in[4];
  const float* wts = (const float*)d_in[5];
  const float* Tsv = (const float*)d_in[6];
  float* out = (float*)d_out;

  char* ws = (char*)d_ws;
  float* models = (float*)ws;                                        // 64*256*12 f32 = 768 KiB
  int* counts   = (int*)(ws + (size_t)NBATCH * NITER * 12 * 4);      // 64*256 i32  = 64 KiB
  int* win      = (int*)((char*)counts + (size_t)NBATCH * NITER * 4);// 64 i32

  hipMemsetAsync(counts, 0, (size_t)NBATCH * NITER * sizeof(int), stream);
  fit_kernel<<<NBATCH, NITER, 0, stream>>>(src, trg, wts, Tsv, models);
  count_kernel<<<NBATCH * (NPTS / (256 * PPT)), 256, 0, stream>>>(src, trg, vs, vt, models, counts);
  argmax_kernel<<<NBATCH, 64, 0, stream>>>(counts, win);
  output_kernel<<<(NBATCH * NPTS) / 256, 256, 0, stream>>>(src, trg, vs, vt, models, win, out);
}

// Round 7
// 229.586 us; speedup vs baseline: 1.2405x; 1.2405x over previous
//
#include <hip/hip_runtime.h>
#include <stdint.h>
#include <math.h>

#define NPTS   16384
#define NBATCH 64
#define NITER  256
#define NSAMP  6
#define PPT    8
#define NCHUNK 8          // point chunks (256 thr * PPT pts each)
#define ISPLIT 4          // iteration splits
#define IPB    (NITER / ISPLIT)   // iterations per block = 64

// ---------------- Threefry-2x32 (exact JAX semantics) ----------------
__device__ __forceinline__ uint32_t rotl32(uint32_t v, uint32_t r) {
  return (v << r) | (v >> (32u - r));
}
__device__ __forceinline__ void tf_round(uint32_t& x0, uint32_t& x1, uint32_t r) {
  x0 += x1; x1 = rotl32(x1, r); x1 ^= x0;
}
__device__ void threefry2x32(uint32_t k0, uint32_t k1, uint32_t x0, uint32_t x1,
                             uint32_t& o0, uint32_t& o1) {
  uint32_t ks2 = k0 ^ k1 ^ 0x1BD11BDAu;
  x0 += k0; x1 += k1;
  tf_round(x0,x1,13); tf_round(x0,x1,15); tf_round(x0,x1,26); tf_round(x0,x1,6);
  x0 += k1; x1 += ks2 + 1u;
  tf_round(x0,x1,17); tf_round(x0,x1,29); tf_round(x0,x1,16); tf_round(x0,x1,24);
  x0 += ks2; x1 += k0 + 2u;
  tf_round(x0,x1,13); tf_round(x0,x1,15); tf_round(x0,x1,26); tf_round(x0,x1,6);
  x0 += k0; x1 += k1 + 3u;
  tf_round(x0,x1,17); tf_round(x0,x1,29); tf_round(x0,x1,16); tf_round(x0,x1,24);
  x0 += k1; x1 += ks2 + 4u;
  tf_round(x0,x1,13); tf_round(x0,x1,15); tf_round(x0,x1,26); tf_round(x0,x1,6);
  x0 += ks2; x1 += k0 + 5u;
  o0 = x0; o1 = x1;
}

// ---------------- 3x3 Jacobi rotation (compile-time indices) ----------------
template<int P, int Q>
__device__ __forceinline__ void jrot(double S[3][3], double V[3][3]) {
  double apq = S[P][Q];
  if (fabs(apq) > 1e-300) {
    double tau = (S[Q][Q] - S[P][P]) / (2.0 * apq);
    double t = copysign(1.0, tau) / (fabs(tau) + sqrt(1.0 + tau * tau));
    double c = 1.0 / sqrt(1.0 + t * t);
    double sn = t * c;
    #pragma unroll
    for (int k = 0; k < 3; ++k) {
      double skp = S[k][P], skq = S[k][Q];
      S[k][P] = c * skp - sn * skq;
      S[k][Q] = sn * skp + c * skq;
    }
    #pragma unroll
    for (int k = 0; k < 3; ++k) {
      double spk = S[P][k], sqk = S[Q][k];
      S[P][k] = c * spk - sn * sqk;
      S[Q][k] = sn * spk + c * sqk;
    }
    #pragma unroll
    for (int k = 0; k < 3; ++k) {
      double vkp = V[k][P], vkq = V[k][Q];
      V[k][P] = c * vkp - sn * vkq;
      V[k][Q] = sn * vkp + c * vkq;
    }
  }
}

__device__ __forceinline__ void swapd(double& a, double& b) { double t=a; a=b; b=t; }

// ---------------- Kernel 1: model fit (one thread per (batch, iter)) ----------------
__global__ __launch_bounds__(256) void fit_kernel(
    const float* __restrict__ src, const float* __restrict__ trg,
    const float* __restrict__ wts, const float* __restrict__ Tsv,
    float* __restrict__ models /* [NBATCH][NITER][12] */) {
  const int b = blockIdx.x;
  const int iter = threadIdx.x;

  // k2 = split(key(42))[1] under partitionable (fold-like) split.
  uint32_t K0, K1;
  threefry2x32(0u, 42u, 0u, 1u, K0, K1);

  const uint32_t base = (uint32_t)((iter * NBATCH + b) * NSAMP);
  int idx[NSAMP];
  #pragma unroll
  for (int s = 0; s < NSAMP; ++s) {
    uint32_t y0, y1;
    threefry2x32(K0, K1, 0u, base + (uint32_t)s, y0, y1);
    idx[s] = (int)((y0 ^ y1) & (uint32_t)(NPTS - 1));
  }

  const float* sb = src + (size_t)b * 4 * NPTS;
  const float* tb = trg + (size_t)b * 4 * NPTS;
  const float* wb = wts + (size_t)b * NPTS;

  float px[NSAMP], py[NSAMP], pz[NSAMP], qx[NSAMP], qy[NSAMP], qz[NSAMP], wv[NSAMP];
  #pragma unroll
  for (int s = 0; s < NSAMP; ++s) {
    int j = idx[s];
    px[s] = sb[j]; py[s] = sb[NPTS + j]; pz[s] = sb[2 * NPTS + j];
    qx[s] = tb[j]; qy[s] = tb[NPTS + j]; qz[s] = tb[2 * NPTS + j];
    wv[s] = wb[j];
  }

  // weighted centroids (fp64)
  double wsum = 0, csx = 0, csy = 0, csz = 0, ctx = 0, cty = 0, ctz = 0;
  #pragma unroll
  for (int s = 0; s < NSAMP; ++s) {
    double w = (double)wv[s];
    wsum += w;
    csx += (double)px[s] * w; csy += (double)py[s] * w; csz += (double)pz[s] * w;
    ctx += (double)qx[s] * w; cty += (double)qy[s] * w; ctz += (double)qz[s] * w;
  }
  double iw = 1.0 / wsum;
  csx *= iw; csy *= iw; csz *= iw; ctx *= iw; cty *= iw; ctz *= iw;

  double C00=0,C01=0,C02=0,C10=0,C11=0,C12=0,C20=0,C21=0,C22=0;
  #pragma unroll
  for (int s = 0; s < NSAMP; ++s) {
    double w = (double)wv[s];
    double ax = ((double)qx[s]-ctx)*w, ay = ((double)qy[s]-cty)*w, az = ((double)qz[s]-ctz)*w;
    double bx = (double)px[s]-csx, by = (double)py[s]-csy, bz = (double)pz[s]-csz;
    C00 += ax*bx; C01 += ax*by; C02 += ax*bz;
    C10 += ay*bx; C11 += ay*by; C12 += ay*bz;
    C20 += az*bx; C21 += az*by; C22 += az*bz;
  }

  // S = C^T C, Jacobi eigendecomposition -> V, eigenvalues on diag.
  // 6 sweeps: quadratic convergence, fp64-converged for 3x3 by sweep ~4.
  double S[3][3], V[3][3] = {{1,0,0},{0,1,0},{0,0,1}};
  S[0][0] = C00*C00 + C10*C10 + C20*C20;
  S[0][1] = C00*C01 + C10*C11 + C20*C21;
  S[0][2] = C00*C02 + C10*C12 + C20*C22;
  S[1][1] = C01*C01 + C11*C11 + C21*C21;
  S[1][2] = C01*C02 + C11*C12 + C21*C22;
  S[2][2] = C02*C02 + C12*C12 + C22*C22;
  S[1][0] = S[0][1]; S[2][0] = S[0][2]; S[2][1] = S[1][2];
  #pragma unroll 1
  for (int sweep = 0; sweep < 6; ++sweep) {
    jrot<0,1>(S, V); jrot<0,2>(S, V); jrot<1,2>(S, V);
  }

  double l0 = S[0][0], l1 = S[1][1], l2 = S[2][2];
  double v0x=V[0][0], v0y=V[1][0], v0z=V[2][0];
  double v1x=V[0][1], v1y=V[1][1], v1z=V[2][1];
  double v2x=V[0][2], v2y=V[1][2], v2z=V[2][2];
  if (l0 < l1) { swapd(l0,l1); swapd(v0x,v1x); swapd(v0y,v1y); swapd(v0z,v1z); }
  if (l1 < l2) { swapd(l1,l2); swapd(v1x,v2x); swapd(v1y,v2y); swapd(v1z,v2z); }
  if (l0 < l1) { swapd(l0,l1); swapd(v0x,v1x); swapd(v0y,v1y); swapd(v0z,v1z); }

  double u0x = C00*v0x + C01*v0y + C02*v0z;
  double u0y = C10*v0x + C11*v0y + C12*v0z;
  double u0z = C20*v0x + C21*v0y + C22*v0z;
  double n0 = sqrt(u0x*u0x + u0y*u0y + u0z*u0z);
  double r0 = (n0 > 1e-150) ? 1.0 / n0 : 0.0;
  u0x *= r0; u0y *= r0; u0z *= r0;
  double u1x = C00*v1x + C01*v1y + C02*v1z;
  double u1y = C10*v1x + C11*v1y + C12*v1z;
  double u1z = C20*v1x + C21*v1y + C22*v1z;
  double d01 = u1x*u0x + u1y*u0y + u1z*u0z;
  u1x -= d01*u0x; u1y -= d01*u0y; u1z -= d01*u0z;
  double n1 = sqrt(u1x*u1x + u1y*u1y + u1z*u1z);
  double r1 = (n1 > 1e-150) ? 1.0 / n1 : 0.0;
  u1x *= r1; u1y *= r1; u1z *= r1;
  double u2x = u0y*u1z - u0z*u1y;
  double u2y = u0z*u1x - u0x*u1z;
  double u2z = u0x*u1y - u0y*u1x;
  double detV = v0x*(v1y*v2z - v1z*v2y) - v0y*(v1x*v2z - v1z*v2x) + v0z*(v1x*v2y - v1y*v2x);
  double R00 = u0x*v0x + u1x*v1x + detV*u2x*v2x;
  double R01 = u0x*v0y + u1x*v1y + detV*u2x*v2y;
  double R02 = u0x*v0z + u1x*v1z + detV*u2x*v2z;
  double R10 = u0y*v0x + u1y*v1x + detV*u2y*v2x;
  double R11 = u0y*v0y + u1y*v1y + detV*u2y*v2y;
  double R12 = u0y*v0z + u1y*v1z + detV*u2y*v2z;
  double R20 = u0z*v0x + u1z*v1x + detV*u2z*v2x;
  double R21 = u0z*v0y + u1z*v1y + detV*u2z*v2y;
  double R22 = u0z*v0z + u1z*v1z + detV*u2z*v2z;
  double tx = ctx - (R00*csx + R01*csy + R02*csz);
  double ty = cty - (R10*csx + R11*csy + R12*csz);
  double tz = ctz - (R20*csx + R21*csy + R22*csz);

  // T_cam = T_s_v @ T_ts @ inv(T_s_v)
  double A[4][4];
  #pragma unroll
  for (int i = 0; i < 4; ++i)
    #pragma unroll
    for (int j = 0; j < 4; ++j) A[i][j] = (double)Tsv[i*4 + j];
  double Tts[4][4] = {{R00,R01,R02,tx},{R10,R11,R12,ty},{R20,R21,R22,tz},{0,0,0,1}};
  double I[4][4];
  I[0][0]=A[0][0]; I[0][1]=A[1][0]; I[0][2]=A[2][0];
  I[1][0]=A[0][1]; I[1][1]=A[1][1]; I[1][2]=A[2][1];
  I[2][0]=A[0][2]; I[2][1]=A[1][2]; I[2][2]=A[2][2];
  I[0][3] = -(I[0][0]*A[0][3] + I[0][1]*A[1][3] + I[0][2]*A[2][3]);
  I[1][3] = -(I[1][0]*A[0][3] + I[1][1]*A[1][3] + I[1][2]*A[2][3]);
  I[2][3] = -(I[2][0]*A[0][3] + I[2][1]*A[1][3] + I[2][2]*A[2][3]);
  I[3][0]=0; I[3][1]=0; I[3][2]=0; I[3][3]=1;
  double M1[4][4];
  #pragma unroll
  for (int i = 0; i < 4; ++i)
    #pragma unroll
    for (int j = 0; j < 4; ++j)
      M1[i][j] = A[i][0]*Tts[0][j] + A[i][1]*Tts[1][j] + A[i][2]*Tts[2][j] + A[i][3]*Tts[3][j];
  float* mo = models + ((size_t)b * NITER + iter) * 12;
  #pragma unroll
  for (int i = 0; i < 3; ++i)
    #pragma unroll
    for (int j = 0; j < 4; ++j)
      mo[i*4 + j] = (float)(M1[i][0]*I[0][j] + M1[i][1]*I[1][j] + M1[i][2]*I[2][j] + M1[i][3]*I[3][j]);
}

// ---------------- Kernel 2: inlier counts ----------------
// Grid: NBATCH * ISPLIT * NCHUNK blocks. Each block: IPB iterations x (256*PPT) points.
// ITER_SPLIT=4 lifts occupancy from 2 to 8 blocks/CU (was the round-4 bottleneck:
// OccupancyPercent 21%, VALUBusy 49%).
__global__ __launch_bounds__(256) void count_kernel(
    const float* __restrict__ src, const float* __restrict__ trg,
    const int* __restrict__ vs, const int* __restrict__ vt,
    const float* __restrict__ models, int* __restrict__ counts) {
  __shared__ float M[IPB * 12];
  __shared__ int cl[IPB];
  const int b      = blockIdx.x >> 5;
  const int isplit = (blockIdx.x >> 3) & (ISPLIT - 1);
  const int chunk  = blockIdx.x & (NCHUNK - 1);
  const int ibase  = isplit * IPB;

  const float* mb = models + ((size_t)b * NITER + ibase) * 12;
  for (int i = threadIdx.x; i < IPB * 12; i += 256) M[i] = mb[i];
  if (threadIdx.x < IPB) cl[threadIdx.x] = 0;
  __syncthreads();

  const float* sb = src + (size_t)b * 4 * NPTS;
  const float* tb = trg + (size_t)b * 4 * NPTS;
  const int* vsb = vs + (size_t)b * NPTS;
  const int* vtb = vt + (size_t)b * NPTS;
  const int p0 = chunk * (256 * PPT) + threadIdx.x;

  float sx[PPT], sy[PPT], sz[PPT], tx[PPT], ty[PPT], tz[PPT];
  bool vd[PPT];
  #pragma unroll
  for (int k = 0; k < PPT; ++k) {
    int p = p0 + k * 256;
    sx[k] = sb[p]; sy[k] = sb[NPTS + p]; sz[k] = sb[2 * NPTS + p];
    tx[k] = tb[p]; ty[k] = tb[NPTS + p]; tz[k] = tb[2 * NPTS + p];
    vd[k] = (vsb[p] > 0) && (vtb[p] > 0);
  }

  for (int it = 0; it < IPB; ++it) {
    const float* m = &M[it * 12];
    float m00=m[0], m01=m[1], m02=m[2],  m03=m[3];
    float m10=m[4], m11=m[5], m12=m[6],  m13=m[7];
    float m20=m[8], m21=m[9], m22=m[10], m23=m[11];
    int c = 0;
    #pragma unroll
    for (int k = 0; k < PPT; ++k) {
      float ex = fmaf(m00, sx[k], fmaf(m01, sy[k], fmaf(m02, sz[k], m03)));
      float ey = fmaf(m10, sx[k], fmaf(m11, sy[k], fmaf(m12, sz[k], m13)));
      float ez = fmaf(m20, sx[k], fmaf(m21, sy[k], fmaf(m22, sz[k], m23)));
      float dx = tx[k] - ex, dy = ty[k] - ey, dz = tz[k] - ez;
      float e2 = fmaf(dx, dx, fmaf(dy, dy, dz * dz));
      c += (e2 < 0.25f && vd[k]) ? 1 : 0;
    }
    c += __shfl_xor(c, 32); c += __shfl_xor(c, 16); c += __shfl_xor(c, 8);
    c += __shfl_xor(c, 4);  c += __shfl_xor(c, 2);  c += __shfl_xor(c, 1);
    if ((threadIdx.x & 63) == 0) atomicAdd(&cl[it], c);
  }
  __syncthreads();
  if (threadIdx.x < IPB)
    atomicAdd(&counts[(size_t)b * NITER + ibase + threadIdx.x], cl[threadIdx.x]);
}

// ---------------- Kernel 3: argmax (strict >, first max wins) ----------------
__global__ __launch_bounds__(64) void argmax_kernel(const int* __restrict__ counts,
                                                    int* __restrict__ win) {
  const int b = blockIdx.x;
  int best = -1;
  for (int it = threadIdx.x; it < NITER; it += 64) {
    int c = counts[b * NITER + it];
    int key = (c << 8) | (NITER - 1 - it);  // max count, then earliest iter
    best = max(best, key);
  }
  best = max(best, __shfl_xor(best, 32));
  best = max(best, __shfl_xor(best, 16));
  best = max(best, __shfl_xor(best, 8));
  best = max(best, __shfl_xor(best, 4));
  best = max(best, __shfl_xor(best, 2));
  best = max(best, __shfl_xor(best, 1));
  if (threadIdx.x == 0) win[b] = (NITER - 1) - (best & 255);
}

// ---------------- Kernel 4: write winning mask ----------------
__global__ __launch_bounds__(256) void output_kernel(
    const float* __restrict__ src, const float* __restrict__ trg,
    const int* __restrict__ vs, const int* __restrict__ vt,
    const float* __restrict__ models, const int* __restrict__ win,
    float* __restrict__ out) {
  const int tid = blockIdx.x * 256 + threadIdx.x;
  const int b = tid >> 14;
  const int p = tid & (NPTS - 1);
  const int it = win[b];
  const float* m = models + ((size_t)b * NITER + it) * 12;
  float m00=m[0], m01=m[1], m02=m[2],  m03=m[3];
  float m10=m[4], m11=m[5], m12=m[6],  m13=m[7];
  float m20=m[8], m21=m[9], m22=m[10], m23=m[11];
  const float* sb = src + (size_t)b * 4 * NPTS;
  const float* tb = trg + (size_t)b * 4 * NPTS;
  float sxv = sb[p], syv = sb[NPTS + p], szv = sb[2 * NPTS + p];
  float txv = tb[p], tyv = tb[NPTS + p], tzv = tb[2 * NPTS + p];
  bool v = (vs[(size_t)b * NPTS + p] > 0) && (vt[(size_t)b * NPTS + p] > 0);
  float ex = fmaf(m00, sxv, fmaf(m01, syv, fmaf(m02, szv, m03)));
  float ey = fmaf(m10, sxv, fmaf(m11, syv, fmaf(m12, szv, m13)));
  float ez = fmaf(m20, sxv, fmaf(m21, syv, fmaf(m22, szv, m23)));
  float dx = txv - ex, dy = tyv - ey, dz = tzv - ez;
  float e2 = fmaf(dx, dx, fmaf(dy, dy, dz * dz));
  out[tid] = (e2 < 0.25f && v) ? 1.0f : 0.0f;
}

extern "C" void kernel_launch(void* const* d_in, const int* in_sizes, int n_in,
                              void* d_out, int out_size, void* d_ws, size_t ws_size,
                              hipStream_t stream) {
  (void)in_sizes; (void)n_in; (void)out_size; (void)ws_size;
  const float* src = (const float*)d_in[0];
  const float* trg = (const float*)d_in[1];
  // d_in[2] = keypoints_2D_trg, unused (DIM == '3D')
  const int*   vs  = (const int*)d_in[3];
  const int*   vt  = (const int*)d_in[4];
  const float* wts = (const float*)d_in[5];
  const float* Tsv = (const float*)d_in[6];
  float* out = (float*)d_out;

  char* ws = (char*)d_ws;
  float* models = (float*)ws;                                        // 64*256*12 f32 = 768 KiB
  int* counts   = (int*)(ws + (size_t)NBATCH * NITER * 12 * 4);      // 64*256 i32  = 64 KiB
  int* win      = (int*)((char*)counts + (size_t)NBATCH * NITER * 4);// 64 i32

  hipMemsetAsync(counts, 0, (size_t)NBATCH * NITER * sizeof(int), stream);
  fit_kernel<<<NBATCH, NITER, 0, stream>>>(src, trg, wts, Tsv, models);
  count_kernel<<<NBATCH * ISPLIT * NCHUNK, 256, 0, stream>>>(src, trg, vs, vt, models, counts);
  argmax_kernel<<<NBATCH, 64, 0, stream>>>(counts, win);
  output_kernel<<<(NBATCH * NPTS) / 256, 256, 0, stream>>>(src, trg, vs, vt, models, win, out);
}

// Round 8
// 215.144 us; speedup vs baseline: 1.3237x; 1.0671x over previous
//
#include <hip/hip_runtime.h>
#include <stdint.h>
#include <math.h>

#define NPTS   16384
#define NBATCH 64
#define NITER  256
#define NSAMP  6
#define PPT    8
#define NCHUNK 8          // point chunks (256 thr * PPT pts each)
#define ISPLIT 4          // iteration splits
#define IPB    (NITER / ISPLIT)   // iterations per block = 64

// ---------------- Threefry-2x32 (exact JAX semantics) ----------------
__device__ __forceinline__ uint32_t rotl32(uint32_t v, uint32_t r) {
  return (v << r) | (v >> (32u - r));
}
__device__ __forceinline__ void tf_round(uint32_t& x0, uint32_t& x1, uint32_t r) {
  x0 += x1; x1 = rotl32(x1, r); x1 ^= x0;
}
__device__ void threefry2x32(uint32_t k0, uint32_t k1, uint32_t x0, uint32_t x1,
                             uint32_t& o0, uint32_t& o1) {
  uint32_t ks2 = k0 ^ k1 ^ 0x1BD11BDAu;
  x0 += k0; x1 += k1;
  tf_round(x0,x1,13); tf_round(x0,x1,15); tf_round(x0,x1,26); tf_round(x0,x1,6);
  x0 += k1; x1 += ks2 + 1u;
  tf_round(x0,x1,17); tf_round(x0,x1,29); tf_round(x0,x1,16); tf_round(x0,x1,24);
  x0 += ks2; x1 += k0 + 2u;
  tf_round(x0,x1,13); tf_round(x0,x1,15); tf_round(x0,x1,26); tf_round(x0,x1,6);
  x0 += k0; x1 += k1 + 3u;
  tf_round(x0,x1,17); tf_round(x0,x1,29); tf_round(x0,x1,16); tf_round(x0,x1,24);
  x0 += k1; x1 += ks2 + 4u;
  tf_round(x0,x1,13); tf_round(x0,x1,15); tf_round(x0,x1,26); tf_round(x0,x1,6);
  x0 += ks2; x1 += k0 + 5u;
  o0 = x0; o1 = x1;
}

// ---------------- 3x3 Jacobi rotation (compile-time indices) ----------------
template<int P, int Q>
__device__ __forceinline__ void jrot(double S[3][3], double V[3][3]) {
  double apq = S[P][Q];
  if (fabs(apq) > 1e-300) {
    double tau = (S[Q][Q] - S[P][P]) / (2.0 * apq);
    double t = copysign(1.0, tau) / (fabs(tau) + sqrt(1.0 + tau * tau));
    double c = 1.0 / sqrt(1.0 + t * t);
    double sn = t * c;
    #pragma unroll
    for (int k = 0; k < 3; ++k) {
      double skp = S[k][P], skq = S[k][Q];
      S[k][P] = c * skp - sn * skq;
      S[k][Q] = sn * skp + c * skq;
    }
    #pragma unroll
    for (int k = 0; k < 3; ++k) {
      double spk = S[P][k], sqk = S[Q][k];
      S[P][k] = c * spk - sn * sqk;
      S[Q][k] = sn * spk + c * sqk;
    }
    #pragma unroll
    for (int k = 0; k < 3; ++k) {
      double vkp = V[k][P], vkq = V[k][Q];
      V[k][P] = c * vkp - sn * vkq;
      V[k][Q] = sn * vkp + c * vkq;
    }
  }
}

__device__ __forceinline__ void swapd(double& a, double& b) { double t=a; a=b; b=t; }

// ---------------- Kernel 1: model fit (one thread per (batch, iter)) ----------------
// 256 blocks x 64 threads: 4x the CU coverage of the old 64x256 layout for this
// latency-bound fp64 chain. Also zeroes `counts` (replaces the memset dispatch).
__global__ __launch_bounds__(64) void fit_kernel(
    const float* __restrict__ src, const float* __restrict__ trg,
    const float* __restrict__ wts, const float* __restrict__ Tsv,
    float* __restrict__ models /* [NBATCH][NITER][12] */,
    int* __restrict__ counts /* [NBATCH][NITER] */) {
  const int b = blockIdx.x >> 2;
  const int iter = ((blockIdx.x & 3) << 6) | threadIdx.x;

  counts[b * NITER + iter] = 0;

  // k2 = split(key(42))[1] under partitionable (fold-like) split.
  uint32_t K0, K1;
  threefry2x32(0u, 42u, 0u, 1u, K0, K1);

  const uint32_t base = (uint32_t)((iter * NBATCH + b) * NSAMP);
  int idx[NSAMP];
  #pragma unroll
  for (int s = 0; s < NSAMP; ++s) {
    uint32_t y0, y1;
    threefry2x32(K0, K1, 0u, base + (uint32_t)s, y0, y1);
    idx[s] = (int)((y0 ^ y1) & (uint32_t)(NPTS - 1));
  }

  const float* sb = src + (size_t)b * 4 * NPTS;
  const float* tb = trg + (size_t)b * 4 * NPTS;
  const float* wb = wts + (size_t)b * NPTS;

  float px[NSAMP], py[NSAMP], pz[NSAMP], qx[NSAMP], qy[NSAMP], qz[NSAMP], wv[NSAMP];
  #pragma unroll
  for (int s = 0; s < NSAMP; ++s) {
    int j = idx[s];
    px[s] = sb[j]; py[s] = sb[NPTS + j]; pz[s] = sb[2 * NPTS + j];
    qx[s] = tb[j]; qy[s] = tb[NPTS + j]; qz[s] = tb[2 * NPTS + j];
    wv[s] = wb[j];
  }

  // weighted centroids (fp64)
  double wsum = 0, csx = 0, csy = 0, csz = 0, ctx = 0, cty = 0, ctz = 0;
  #pragma unroll
  for (int s = 0; s < NSAMP; ++s) {
    double w = (double)wv[s];
    wsum += w;
    csx += (double)px[s] * w; csy += (double)py[s] * w; csz += (double)pz[s] * w;
    ctx += (double)qx[s] * w; cty += (double)qy[s] * w; ctz += (double)qz[s] * w;
  }
  double iw = 1.0 / wsum;
  csx *= iw; csy *= iw; csz *= iw; ctx *= iw; cty *= iw; ctz *= iw;

  double C00=0,C01=0,C02=0,C10=0,C11=0,C12=0,C20=0,C21=0,C22=0;
  #pragma unroll
  for (int s = 0; s < NSAMP; ++s) {
    double w = (double)wv[s];
    double ax = ((double)qx[s]-ctx)*w, ay = ((double)qy[s]-cty)*w, az = ((double)qz[s]-ctz)*w;
    double bx = (double)px[s]-csx, by = (double)py[s]-csy, bz = (double)pz[s]-csz;
    C00 += ax*bx; C01 += ax*by; C02 += ax*bz;
    C10 += ay*bx; C11 += ay*by; C12 += ay*bz;
    C20 += az*bx; C21 += az*by; C22 += az*bz;
  }

  // S = C^T C, Jacobi eigendecomposition -> V, eigenvalues on diag.
  double S[3][3], V[3][3] = {{1,0,0},{0,1,0},{0,0,1}};
  S[0][0] = C00*C00 + C10*C10 + C20*C20;
  S[0][1] = C00*C01 + C10*C11 + C20*C21;
  S[0][2] = C00*C02 + C10*C12 + C20*C22;
  S[1][1] = C01*C01 + C11*C11 + C21*C21;
  S[1][2] = C01*C02 + C11*C12 + C21*C22;
  S[2][2] = C02*C02 + C12*C12 + C22*C22;
  S[1][0] = S[0][1]; S[2][0] = S[0][2]; S[2][1] = S[1][2];
  #pragma unroll 1
  for (int sweep = 0; sweep < 6; ++sweep) {
    jrot<0,1>(S, V); jrot<0,2>(S, V); jrot<1,2>(S, V);
  }

  double l0 = S[0][0], l1 = S[1][1], l2 = S[2][2];
  double v0x=V[0][0], v0y=V[1][0], v0z=V[2][0];
  double v1x=V[0][1], v1y=V[1][1], v1z=V[2][1];
  double v2x=V[0][2], v2y=V[1][2], v2z=V[2][2];
  if (l0 < l1) { swapd(l0,l1); swapd(v0x,v1x); swapd(v0y,v1y); swapd(v0z,v1z); }
  if (l1 < l2) { swapd(l1,l2); swapd(v1x,v2x); swapd(v1y,v2y); swapd(v1z,v2z); }
  if (l0 < l1) { swapd(l0,l1); swapd(v0x,v1x); swapd(v0y,v1y); swapd(v0z,v1z); }

  double u0x = C00*v0x + C01*v0y + C02*v0z;
  double u0y = C10*v0x + C11*v0y + C12*v0z;
  double u0z = C20*v0x + C21*v0y + C22*v0z;
  double n0 = sqrt(u0x*u0x + u0y*u0y + u0z*u0z);
  double r0 = (n0 > 1e-150) ? 1.0 / n0 : 0.0;
  u0x *= r0; u0y *= r0; u0z *= r0;
  double u1x = C00*v1x + C01*v1y + C02*v1z;
  double u1y = C10*v1x + C11*v1y + C12*v1z;
  double u1z = C20*v1x + C21*v1y + C22*v1z;
  double d01 = u1x*u0x + u1y*u0y + u1z*u0z;
  u1x -= d01*u0x; u1y -= d01*u0y; u1z -= d01*u0z;
  double n1 = sqrt(u1x*u1x + u1y*u1y + u1z*u1z);
  double r1 = (n1 > 1e-150) ? 1.0 / n1 : 0.0;
  u1x *= r1; u1y *= r1; u1z *= r1;
  double u2x = u0y*u1z - u0z*u1y;
  double u2y = u0z*u1x - u0x*u1z;
  double u2z = u0x*u1y - u0y*u1x;
  double detV = v0x*(v1y*v2z - v1z*v2y) - v0y*(v1x*v2z - v1z*v2x) + v0z*(v1x*v2y - v1y*v2x);
  double R00 = u0x*v0x + u1x*v1x + detV*u2x*v2x;
  double R01 = u0x*v0y + u1x*v1y + detV*u2x*v2y;
  double R02 = u0x*v0z + u1x*v1z + detV*u2x*v2z;
  double R10 = u0y*v0x + u1y*v1x + detV*u2y*v2x;
  double R11 = u0y*v0y + u1y*v1y + detV*u2y*v2y;
  double R12 = u0y*v0z + u1y*v1z + detV*u2y*v2z;
  double R20 = u0z*v0x + u1z*v1x + detV*u2z*v2x;
  double R21 = u0z*v0y + u1z*v1y + detV*u2z*v2y;
  double R22 = u0z*v0z + u1z*v1z + detV*u2z*v2z;
  double tx = ctx - (R00*csx + R01*csy + R02*csz);
  double ty = cty - (R10*csx + R11*csy + R12*csz);
  double tz = ctz - (R20*csx + R21*csy + R22*csz);

  // T_cam = T_s_v @ T_ts @ inv(T_s_v)
  double A[4][4];
  #pragma unroll
  for (int i = 0; i < 4; ++i)
    #pragma unroll
    for (int j = 0; j < 4; ++j) A[i][j] = (double)Tsv[i*4 + j];
  double Tts[4][4] = {{R00,R01,R02,tx},{R10,R11,R12,ty},{R20,R21,R22,tz},{0,0,0,1}};
  double I[4][4];
  I[0][0]=A[0][0]; I[0][1]=A[1][0]; I[0][2]=A[2][0];
  I[1][0]=A[0][1]; I[1][1]=A[1][1]; I[1][2]=A[2][1];
  I[2][0]=A[0][2]; I[2][1]=A[1][2]; I[2][2]=A[2][2];
  I[0][3] = -(I[0][0]*A[0][3] + I[0][1]*A[1][3] + I[0][2]*A[2][3]);
  I[1][3] = -(I[1][0]*A[0][3] + I[1][1]*A[1][3] + I[1][2]*A[2][3]);
  I[2][3] = -(I[2][0]*A[0][3] + I[2][1]*A[1][3] + I[2][2]*A[2][3]);
  I[3][0]=0; I[3][1]=0; I[3][2]=0; I[3][3]=1;
  double M1[4][4];
  #pragma unroll
  for (int i = 0; i < 4; ++i)
    #pragma unroll
    for (int j = 0; j < 4; ++j)
      M1[i][j] = A[i][0]*Tts[0][j] + A[i][1]*Tts[1][j] + A[i][2]*Tts[2][j] + A[i][3]*Tts[3][j];
  float* mo = models + ((size_t)b * NITER + iter) * 12;
  #pragma unroll
  for (int i = 0; i < 3; ++i)
    #pragma unroll
    for (int j = 0; j < 4; ++j)
      mo[i*4 + j] = (float)(M1[i][0]*I[0][j] + M1[i][1]*I[1][j] + M1[i][2]*I[2][j] + M1[i][3]*I[3][j]);
}

// ---------------- Kernel 2: inlier counts ----------------
// R7 counters: VALUBusy 71% -- the stall is the 3 dependent ds_read_b128 model
// broadcasts (~120cyc) serialized ahead of each iteration's ~224cyc of VALU.
// Fix: double-buffered model registers (prefetch M[it+1] during compute of it)
// + unroll 2 so the next iteration's VALU overlaps this one's swizzle chain.
__global__ __launch_bounds__(256) void count_kernel(
    const float* __restrict__ src, const float* __restrict__ trg,
    const int* __restrict__ vs, const int* __restrict__ vt,
    const float* __restrict__ models, int* __restrict__ counts) {
  __shared__ float M[IPB * 12];
  __shared__ int cl[IPB];
  const int b      = blockIdx.x >> 5;
  const int isplit = (blockIdx.x >> 3) & (ISPLIT - 1);
  const int chunk  = blockIdx.x & (NCHUNK - 1);
  const int ibase  = isplit * IPB;

  const float* mb = models + ((size_t)b * NITER + ibase) * 12;
  for (int i = threadIdx.x; i < IPB * 12; i += 256) M[i] = mb[i];
  if (threadIdx.x < IPB) cl[threadIdx.x] = 0;
  __syncthreads();

  const float* sb = src + (size_t)b * 4 * NPTS;
  const float* tb = trg + (size_t)b * 4 * NPTS;
  const int* vsb = vs + (size_t)b * NPTS;
  const int* vtb = vt + (size_t)b * NPTS;
  const int p0 = chunk * (256 * PPT) + threadIdx.x;

  float sx[PPT], sy[PPT], sz[PPT], tx[PPT], ty[PPT], tz[PPT];
  bool vd[PPT];
  #pragma unroll
  for (int k = 0; k < PPT; ++k) {
    int p = p0 + k * 256;
    sx[k] = sb[p]; sy[k] = sb[NPTS + p]; sz[k] = sb[2 * NPTS + p];
    tx[k] = tb[p]; ty[k] = tb[NPTS + p]; tz[k] = tb[2 * NPTS + p];
    vd[k] = (vsb[p] > 0) && (vtb[p] > 0);
  }

  float cur[12];
  #pragma unroll
  for (int j = 0; j < 12; ++j) cur[j] = M[j];

  #pragma unroll 2
  for (int it = 0; it < IPB; ++it) {
    // prefetch next model into regs; ds_reads overlap this iteration's compute
    const int nit = (it + 1 < IPB) ? it + 1 : it;
    float nxt[12];
    #pragma unroll
    for (int j = 0; j < 12; ++j) nxt[j] = M[nit * 12 + j];

    float m00=cur[0], m01=cur[1], m02=cur[2],  m03=cur[3];
    float m10=cur[4], m11=cur[5], m12=cur[6],  m13=cur[7];
    float m20=cur[8], m21=cur[9], m22=cur[10], m23=cur[11];
    int c = 0;
    #pragma unroll
    for (int k = 0; k < PPT; ++k) {
      float ex = fmaf(m00, sx[k], fmaf(m01, sy[k], fmaf(m02, sz[k], m03)));
      float ey = fmaf(m10, sx[k], fmaf(m11, sy[k], fmaf(m12, sz[k], m13)));
      float ez = fmaf(m20, sx[k], fmaf(m21, sy[k], fmaf(m22, sz[k], m23)));
      float dx = tx[k] - ex, dy = ty[k] - ey, dz = tz[k] - ez;
      float e2 = fmaf(dx, dx, fmaf(dy, dy, dz * dz));
      c += (e2 < 0.25f && vd[k]) ? 1 : 0;
    }
    c += __shfl_xor(c, 32); c += __shfl_xor(c, 16); c += __shfl_xor(c, 8);
    c += __shfl_xor(c, 4);  c += __shfl_xor(c, 2);  c += __shfl_xor(c, 1);
    if ((threadIdx.x & 63) == 0) atomicAdd(&cl[it], c);

    #pragma unroll
    for (int j = 0; j < 12; ++j) cur[j] = nxt[j];
  }
  __syncthreads();
  if (threadIdx.x < IPB)
    atomicAdd(&counts[(size_t)b * NITER + ibase + threadIdx.x], cl[threadIdx.x]);
}

// ---------------- Kernel 3: argmax (fused) + write winning mask ----------------
// Each block serves one batch's 4096-point slice; it re-derives the argmax from
// the 256 counts itself (1 KB, L2-hot) -- saves a separate dispatch.
__global__ __launch_bounds__(256) void output_kernel(
    const float* __restrict__ src, const float* __restrict__ trg,
    const int* __restrict__ vs, const int* __restrict__ vt,
    const float* __restrict__ models, const int* __restrict__ counts,
    float* __restrict__ out) {
  const int tid = blockIdx.x * 256 + threadIdx.x;
  const int b = tid >> 14;
  const int p = tid & (NPTS - 1);

  // block-wide argmax over 256 iterations (strict >, first max wins)
  __shared__ int sbest[4];
  {
    int c = counts[b * NITER + threadIdx.x];
    int key = (c << 8) | (NITER - 1 - threadIdx.x);
    key = max(key, __shfl_xor(key, 32));
    key = max(key, __shfl_xor(key, 16));
    key = max(key, __shfl_xor(key, 8));
    key = max(key, __shfl_xor(key, 4));
    key = max(key, __shfl_xor(key, 2));
    key = max(key, __shfl_xor(key, 1));
    if ((threadIdx.x & 63) == 0) sbest[threadIdx.x >> 6] = key;
  }
  __syncthreads();
  const int best = max(max(sbest[0], sbest[1]), max(sbest[2], sbest[3]));
  const int it = (NITER - 1) - (best & 255);

  const float* m = models + ((size_t)b * NITER + it) * 12;
  float m00=m[0], m01=m[1], m02=m[2],  m03=m[3];
  float m10=m[4], m11=m[5], m12=m[6],  m13=m[7];
  float m20=m[8], m21=m[9], m22=m[10], m23=m[11];
  const float* sb = src + (size_t)b * 4 * NPTS;
  const float* tb = trg + (size_t)b * 4 * NPTS;
  float sxv = sb[p], syv = sb[NPTS + p], szv = sb[2 * NPTS + p];
  float txv = tb[p], tyv = tb[NPTS + p], tzv = tb[2 * NPTS + p];
  bool v = (vs[(size_t)b * NPTS + p] > 0) && (vt[(size_t)b * NPTS + p] > 0);
  float ex = fmaf(m00, sxv, fmaf(m01, syv, fmaf(m02, szv, m03)));
  float ey = fmaf(m10, sxv, fmaf(m11, syv, fmaf(m12, szv, m13)));
  float ez = fmaf(m20, sxv, fmaf(m21, syv, fmaf(m22, szv, m23)));
  float dx = txv - ex, dy = tyv - ey, dz = tzv - ez;
  float e2 = fmaf(dx, dx, fmaf(dy, dy, dz * dz));
  out[tid] = (e2 < 0.25f && v) ? 1.0f : 0.0f;
}

extern "C" void kernel_launch(void* const* d_in, const int* in_sizes, int n_in,
                              void* d_out, int out_size, void* d_ws, size_t ws_size,
                              hipStream_t stream) {
  (void)in_sizes; (void)n_in; (void)out_size; (void)ws_size;
  const float* src = (const float*)d_in[0];
  const float* trg = (const float*)d_in[1];
  // d_in[2] = keypoints_2D_trg, unused (DIM == '3D')
  const int*   vs  = (const int*)d_in[3];
  const int*   vt  = (const int*)d_in[4];
  const float* wts = (const float*)d_in[5];
  const float* Tsv = (const float*)d_in[6];
  float* out = (float*)d_out;

  char* ws = (char*)d_ws;
  float* models = (float*)ws;                                        // 64*256*12 f32 = 768 KiB
  int* counts   = (int*)(ws + (size_t)NBATCH * NITER * 12 * 4);      // 64*256 i32  = 64 KiB

  fit_kernel<<<NBATCH * 4, 64, 0, stream>>>(src, trg, wts, Tsv, models, counts);
  count_kernel<<<NBATCH * ISPLIT * NCHUNK, 256, 0, stream>>>(src, trg, vs, vt, models, counts);
  output_kernel<<<(NBATCH * NPTS) / 256, 256, 0, stream>>>(src, trg, vs, vt, models, counts, out);
}